// Round 2
// baseline (364.243 us; speedup 1.0000x reference)
//
#include <hip/hip_runtime.h>

// Problem constants (fixed by the reference):
constexpr int Bn = 8;     // batch
constexpr int En = 8;     // experts
constexpr int Cn = 1024;  // capacity
constexpr int In = 128;   // in features (K)
constexpr int On = 256;   // out features (N)
constexpr int Tn = 8192;  // num tokens
constexpr int ECn = En * Cn;  // 8192 contributions per batch

constexpr int TT   = 64;   // tokens per wg -> 1024 wgs
constexpr int EMAX = 48;   // per-(wg,expert) cap; Poisson(8): P(>48) ~ 1e-24
constexpr int FMAX = En * EMAX;  // flat list capacity (384)
constexpr int RSTG = 12;   // staged rows per lane-group -> covers 96 contributions

typedef __fp16 fp16x2 __attribute__((ext_vector_type(2)));
typedef __fp16 f16x8  __attribute__((ext_vector_type(8)));
typedef float  f32x4  __attribute__((ext_vector_type(4)));

__device__ inline unsigned int pk16(float a, float b) {
    fp16x2 h = __builtin_amdgcn_cvt_pkrtz(a, b);   // v_cvt_pkrtz_f16_f32
    return __builtin_bit_cast(unsigned int, h);
}

// CAS-based packed-f16 LDS atomic add (contention ~0: CAS succeeds 1st try).
__device__ inline void casadd(unsigned* p, unsigned v) {
    unsigned old = *p;
    while (true) {
        fp16x2 s = __builtin_bit_cast(fp16x2, old) + __builtin_bit_cast(fp16x2, v);
        unsigned got = atomicCAS(p, old, __builtin_bit_cast(unsigned, s));
        if (got == old) break;
        old = got;
    }
}

// ---------------------------------------------------------------------------
// Pack W (E,O,I) f32 -> f16 B-fragment layout (verified in round 7):
//   wh4[((e*4+s)*4+q)*256 + col] = W[e][col][32s+8q .. +7]  (8 f16 = uint4)
// ---------------------------------------------------------------------------
__global__ void prep_w(const float4* __restrict__ w4, uint4* __restrict__ wh4) {
    int f = blockIdx.x * 256 + threadIdx.x;  // < E*4*4*256 = 32768
    int col = f & 255, q = (f >> 8) & 3, s = (f >> 10) & 3, e = f >> 12;
    const float4* p = w4 + ((size_t)(e * On + col)) * (In / 4) + (s * 8 + q * 2);
    float4 a = p[0], b = p[1];
    uint4 o;
    o.x = pk16(a.x, a.y); o.y = pk16(a.z, a.w);
    o.z = pk16(b.x, b.y); o.w = pk16(b.z, b.w);
    wh4[f] = o;
}

// ---------------------------------------------------------------------------
// Fused MoE, aggregate-then-GEMM, f16-direct aggregation:
//   scan -> flatten -> stage all x rows as gated packed-f16 in VGPRs ->
//   per expert: scatter (pk-f16 CAS adds) into double-buffered frag-layout
//   Ah, MFMA(e) overlapped with zero(e+1). 2 barriers/expert, no f32 A
//   buffer, no convert phase. LDS ~39 KB -> 4 blocks/CU.
// ---------------------------------------------------------------------------
__global__ __launch_bounds__(256, 4)
void fused_moe(const float* __restrict__ x,     // (B,E,C,I) f32
               const int*   __restrict__ idx,   // (B,E,C)
               const float* __restrict__ gate,  // (B,E,C)
               const uint4* __restrict__ wh4,   // packed f16 W (ws)
               const float* __restrict__ bias,  // (O)
               float* __restrict__ out)         // (B,T,O)
{
    __shared__ uint4 Ah[2][TT * 16];                // 2 x 16 KB f16 A, frag-swizzled
    __shared__ unsigned int ent[En][EMAX];          // (tl<<13) | ec
    __shared__ float gat[En][EMAX];
    __shared__ float gsum[TT];
    __shared__ int ecnt[En];
    __shared__ int off[En + 1];                     // prefix offsets
    __shared__ unsigned int fent[FMAX];             // flat (tl<<13)|ec
    __shared__ float fg[FMAX];                      // flat gate

    const int tid = threadIdx.x;
    const int b   = blockIdx.x >> 7;
    const int t0  = (blockIdx.x & 127) * TT;
    const int*   idxb  = idx  + (size_t)b * ECn;
    const float* gateb = gate + (size_t)b * ECn;
    const float* xb    = x + (size_t)b * ECn * In;

    if (tid < En) ecnt[tid] = 0;
    if (tid < TT) gsum[tid] = 0.f;
    __syncthreads();

    // ---- vectorized scan: build per-expert contribution lists + gate sums ----
    {
        const int4* idx4 = (const int4*)idxb;
        #pragma unroll
        for (int s = 0; s < ECn / 1024; ++s) {      // 8 steps of int4
            int i4 = tid + 256 * s;
            int4 tv = idx4[i4];
            int ec0 = i4 * 4;
            #pragma unroll
            for (int k = 0; k < 4; ++k) {
                int t = (k == 0) ? tv.x : (k == 1) ? tv.y : (k == 2) ? tv.z : tv.w;
                unsigned d = (unsigned)(t - t0);
                if (d < (unsigned)TT) {
                    int ec = ec0 + k;
                    float g = gateb[ec];
                    atomicAdd(&gsum[d], g);
                    int e = ec >> 10;
                    int pos = atomicAdd(&ecnt[e], 1);
                    if (pos < EMAX) {
                        ent[e][pos] = (d << 13) | (unsigned)ec;
                        gat[e][pos] = g;
                    }
                }
            }
        }
    }
    __syncthreads();

    // ---- prefix offsets ----
    if (tid == 0) {
        int r = 0;
        #pragma unroll
        for (int e = 0; e < En; ++e) { off[e] = r; r += min(ecnt[e], EMAX); }
        off[En] = r;
    }
    __syncthreads();
    const int total = off[En];   // <= 384

    // ---- flatten lists (expert-segmented flat order) ----
    for (int f = tid; f < total; f += 256) {
        int e = 0;
        #pragma unroll
        for (int k = 1; k < En; ++k) e += (f >= off[k]);
        int j = f - off[e];
        fent[f] = ent[e][j];
        fg[f]   = gat[e][j];
    }
    __syncthreads();

    // ---- stage ALL gather rows as gated packed f16 (one global burst) ----
    // contribution f handled by lane-group (f&7), slot (f>>3); 32 lanes/row,
    // lane l covers k-cols 4l..4l+3 -> 2 packed u32s.
    const int grp = tid >> 5, l = tid & 31;
    uint2 su[RSTG];
    #pragma unroll
    for (int r = 0; r < RSTG; ++r) {
        int f = r * 8 + grp;
        if (f < total) {
            int ec = (int)(fent[f] & 8191u);
            float4 v = ((const float4*)xb)[(size_t)ec * (In / 4) + l];
            float g = fg[f];
            su[r].x = pk16(v.x * g, v.y * g);
            su[r].y = pk16(v.z * g, v.w * g);
        }
    }

    // ---- zero Ah[0] while stage loads drain ----
    for (int i = tid; i < TT * 16; i += 256) Ah[0][i] = uint4{0u, 0u, 0u, 0u};
    __syncthreads();

    const int l15  = tid & 15;        // col-in-tile / row-in-tile
    const int q    = (tid >> 4) & 3;  // lane quad
    const int wcol = (tid >> 6) * 64; // wave's 64-column slab

    f16x8 bfr[4][4];
    auto loadB = [&](int e) {
        #pragma unroll
        for (int nt = 0; nt < 4; ++nt)
            #pragma unroll
            for (int s = 0; s < 4; ++s)
                bfr[nt][s] = __builtin_bit_cast(f16x8,
                    wh4[(size_t)((e * 4 + s) * 4 + q) * 256 + wcol + 16 * nt + l15]);
    };

    // scatter expert e's contributions into Ah[buf] (pk-f16 CAS adds).
    // write mapping: row tl, lane l -> uint4 X=(l>>1)^(tl&15), u32 (l&1)*2+{0,1}
    auto scatter = [&](int e, int buf) {
        const int offE = off[e], offE1 = off[e + 1];
        unsigned* A = (unsigned*)&Ah[buf][0];
        #pragma unroll
        for (int r = 0; r < RSTG; ++r) {
            int f = r * 8 + grp;
            if (f >= offE && f < offE1) {
                int tl = (int)(fent[f] >> 13);
                unsigned* p = A + ((tl * 16 + ((l >> 1) ^ (tl & 15))) << 2) + (l & 1) * 2;
                casadd(p,     su[r].x);
                casadd(p + 1, su[r].y);
            }
        }
        // rare overflow (total > 96): direct global loads, correctness path
        for (int f = RSTG * 8 + grp; f < total; f += 8) {
            if (f >= offE && f < offE1) {
                unsigned en = fent[f];
                int ec = (int)(en & 8191u);
                int tl = (int)(en >> 13);
                float g = fg[f];
                float4 v = ((const float4*)xb)[(size_t)ec * (In / 4) + l];
                unsigned* p = A + ((tl * 16 + ((l >> 1) ^ (tl & 15))) << 2) + (l & 1) * 2;
                casadd(p,     pk16(v.x * g, v.y * g));
                casadd(p + 1, pk16(v.z * g, v.w * g));
            }
        }
    };

    f32x4 acc[4][4];                  // [m-tile][n-tile] = 64 VGPRs
    #pragma unroll
    for (int mt = 0; mt < 4; ++mt)
        #pragma unroll
        for (int nt = 0; nt < 4; ++nt) acc[mt][nt] = f32x4{0.f, 0.f, 0.f, 0.f};

    scatter(0, 0);
    loadB(0);
    __syncthreads();

    // ---- expert pipeline: {mfma(e) | zero(e+1)} bar {scatter(e+1), loadB(e+1)} bar ----
    int cur = 0;
    for (int e = 0; e < En; ++e) {
        #pragma unroll
        for (int mt = 0; mt < 4; ++mt) {
            const int tl = mt * 16 + l15;
            f16x8 afr[4];
            #pragma unroll
            for (int s = 0; s < 4; ++s)
                afr[s] = __builtin_bit_cast(f16x8, Ah[cur][tl * 16 + ((4 * s + q) ^ (tl & 15))]);
            #pragma unroll
            for (int nt = 0; nt < 4; ++nt)
                #pragma unroll
                for (int s = 0; s < 4; ++s)
                    acc[mt][nt] = __builtin_amdgcn_mfma_f32_16x16x32_f16(
                        afr[s], bfr[nt][s], acc[mt][nt], 0, 0, 0);
        }
        if (e < En - 1) {
            for (int i = tid; i < TT * 16; i += 256) Ah[cur ^ 1][i] = uint4{0u, 0u, 0u, 0u};
        }
        __syncthreads();   // zero done; mfma consumed Ah[cur]

        if (e < En - 1) {
            scatter(e + 1, cur ^ 1);  // pure LDS CAS adds from staged regs
            loadB(e + 1);             // L2-hot weight frags for next mfma
        }
        __syncthreads();   // scatter complete before next mfma reads Ah[cur^1]
        cur ^= 1;
    }

    // ---- epilogue: out = acc + gsum*bias (C layout: row=q*4+i, col=l15) ----
    float bv[4];
    #pragma unroll
    for (int nt = 0; nt < 4; ++nt) bv[nt] = bias[wcol + 16 * nt + l15];

    float* ob = out + ((size_t)b * Tn + t0) * On;
    #pragma unroll
    for (int mt = 0; mt < 4; ++mt) {
        #pragma unroll
        for (int i = 0; i < 4; ++i) {
            const int tl = mt * 16 + q * 4 + i;
            const float gs = gsum[tl];
            float* orow = ob + (size_t)tl * On + wcol + l15;
            #pragma unroll
            for (int nt = 0; nt < 4; ++nt)
                orow[16 * nt] = acc[mt][nt][i] + gs * bv[nt];
        }
    }
}

extern "C" void kernel_launch(void* const* d_in, const int* in_sizes, int n_in,
                              void* d_out, int out_size, void* d_ws, size_t ws_size,
                              hipStream_t stream) {
    const float* x    = (const float*)d_in[0];  // (B,E,C,I) fp32
    const int*   idx  = (const int*)  d_in[1];  // (B,E,C) int32
    const float* gate = (const float*)d_in[2];  // (B,E,C) fp32
    const float* w    = (const float*)d_in[3];  // (E,O,I) fp32
    const float* bias = (const float*)d_in[4];  // (O,) fp32
    float* out = (float*)d_out;

    uint4* wh4 = (uint4*)d_ws;  // 512 KB packed f16 weights

    prep_w<<<(En * 4 * 4 * On) / 256, 256, 0, stream>>>((const float4*)w, wh4);

    const int nwg = Bn * (Tn / TT);  // 1024
    fused_moe<<<nwg, 256, 0, stream>>>(x, idx, gate, wh4, bias, out);
}

// Round 3
// 150.954 us; speedup vs baseline: 2.4129x; 2.4129x over previous
//
#include <hip/hip_runtime.h>

// Problem constants (fixed by the reference):
constexpr int Bn = 8;     // batch
constexpr int En = 8;     // experts
constexpr int Cn = 1024;  // capacity
constexpr int In = 128;   // in features (K)
constexpr int On = 256;   // out features (N)
constexpr int Tn = 8192;  // num tokens
constexpr int ECn = En * Cn;

constexpr int TT = 64;    // capacity rows per block tile

typedef __fp16 fp16x2 __attribute__((ext_vector_type(2)));
typedef __fp16 f16x8  __attribute__((ext_vector_type(8)));
typedef float  f32x4  __attribute__((ext_vector_type(4)));

__device__ inline unsigned int pk16(float a, float b) {
    fp16x2 h = __builtin_amdgcn_cvt_pkrtz(a, b);   // v_cvt_pkrtz_f16_f32
    return __builtin_bit_cast(unsigned int, h);
}

// ---------------------------------------------------------------------------
// Pack W (E,O,I) f32 -> f16 B-fragment layout (verified):
//   wh4[((e*4+s)*4+q)*256 + col] = W[e][col][32s+8q .. +7]  (8 f16 = uint4)
// ---------------------------------------------------------------------------
__global__ void prep_w(const float4* __restrict__ w4, uint4* __restrict__ wh4) {
    int f = blockIdx.x * 256 + threadIdx.x;  // < E*4*4*256 = 32768
    int col = f & 255, q = (f >> 8) & 3, s = (f >> 10) & 3, e = f >> 12;
    const float4* p = w4 + ((size_t)(e * On + col)) * (In / 4) + (s * 8 + q * 2);
    float4 a = p[0], b = p[1];
    uint4 o;
    o.x = pk16(a.x, a.y); o.y = pk16(a.z, a.w);
    o.z = pk16(b.x, b.y); o.w = pk16(b.z, b.w);
    wh4[f] = o;
}

// ---------------------------------------------------------------------------
// Dense per-(b,e) GEMM + atomic scatter epilogue.
//   Block = 64 capacity rows x 256 out cols of one (b,e).
//   A rows are CONSECUTIVE x rows (coalesced loads, no gather).
//   out pre-zeroed by hipMemsetAsync; epilogue does
//     atomicAdd(out[b, idx[c], col], (dot + bias[col]) * gate[c])
//   Avg 1.0 adds per out cell -> near-zero contention.
// ---------------------------------------------------------------------------
__global__ __launch_bounds__(256, 2)
void gemm_scatter(const float* __restrict__ x,     // (B,E,C,I) f32
                  const int*   __restrict__ idx,   // (B,E,C)
                  const float* __restrict__ gate,  // (B,E,C)
                  const uint4* __restrict__ wh4,   // packed f16 W
                  const float* __restrict__ bias,  // (O)
                  float* __restrict__ out)         // (B,T,O), pre-zeroed
{
    __shared__ uint4 Ah[TT * 16];   // 16 KB f16 A tile, frag-swizzled
    __shared__ int   sIdx[TT];
    __shared__ float sG[TT];

    const int tid = threadIdx.x;
    const int blk = blockIdx.x;            // (b*8 + e)*16 + mtile
    const int b  = blk >> 7;
    const int e  = (blk >> 4) & 7;
    const int c0 = (blk & 15) * TT;

    const size_t becBase = ((size_t)(b * En + e)) * Cn + c0;
    const float* xrow = x + becBase * In;

    if (tid < TT) {
        sIdx[tid] = idx[becBase + tid];
        sG[tid]   = gate[becBase + tid];
    }

    // ---- stage A: 64 consecutive x rows -> f16 frag-swizzled Ah ----
    // thread (tl = tid>>2, quads cq..cq+3): u32-quad cc covers k = 8cc..8cc+7
    {
        const int tl = tid >> 2, cq = (tid & 3) * 4;
        const float4* xr = (const float4*)xrow + (size_t)tl * (In / 4);
        #pragma unroll
        for (int it = 0; it < 4; ++it) {
            int cc = cq + it;
            float4 a = xr[2 * cc], b2 = xr[2 * cc + 1];
            uint4 o;
            o.x = pk16(a.x, a.y);  o.y = pk16(a.z, a.w);
            o.z = pk16(b2.x, b2.y); o.w = pk16(b2.z, b2.w);
            Ah[tl * 16 + (cc ^ (tl & 15))] = o;   // verified swizzle
        }
    }

    const int l15  = tid & 15;        // col-in-tile / row-in-tile
    const int q    = (tid >> 4) & 3;  // lane quad
    const int wcol = (tid >> 6) * 64; // wave's 64-column slab

    // ---- B fragments for expert e (L2-hot packed weights) ----
    f16x8 bfr[4][4];
    #pragma unroll
    for (int nt = 0; nt < 4; ++nt)
        #pragma unroll
        for (int s = 0; s < 4; ++s)
            bfr[nt][s] = __builtin_bit_cast(f16x8,
                wh4[(size_t)((e * 4 + s) * 4 + q) * 256 + wcol + 16 * nt + l15]);

    __syncthreads();

    // ---- dense MFMA: 64x256 += A(64x128) * W_e(128x256) ----
    f32x4 acc[4][4];
    #pragma unroll
    for (int mt = 0; mt < 4; ++mt)
        #pragma unroll
        for (int nt = 0; nt < 4; ++nt) acc[mt][nt] = f32x4{0.f, 0.f, 0.f, 0.f};

    #pragma unroll
    for (int mt = 0; mt < 4; ++mt) {
        const int tl = mt * 16 + l15;
        f16x8 afr[4];
        #pragma unroll
        for (int s = 0; s < 4; ++s)
            afr[s] = __builtin_bit_cast(f16x8, Ah[tl * 16 + ((4 * s + q) ^ (tl & 15))]);
        #pragma unroll
        for (int nt = 0; nt < 4; ++nt)
            #pragma unroll
            for (int s = 0; s < 4; ++s)
                acc[mt][nt] = __builtin_amdgcn_mfma_f32_16x16x32_f16(
                    afr[s], bfr[nt][s], acc[mt][nt], 0, 0, 0);
    }

    // ---- epilogue: atomic scatter (C layout: row = q*4+i, col = l15) ----
    float bv[4];
    #pragma unroll
    for (int nt = 0; nt < 4; ++nt) bv[nt] = bias[wcol + 16 * nt + l15];

    float* ob = out + (size_t)b * Tn * On;
    #pragma unroll
    for (int mt = 0; mt < 4; ++mt) {
        #pragma unroll
        for (int i = 0; i < 4; ++i) {
            const int tl = mt * 16 + q * 4 + i;
            const int t  = sIdx[tl];
            const float g = sG[tl];
            float* orow = ob + (size_t)t * On + wcol + l15;
            #pragma unroll
            for (int nt = 0; nt < 4; ++nt)
                atomicAdd(&orow[16 * nt], (acc[mt][nt][i] + bv[nt]) * g);
        }
    }
}

extern "C" void kernel_launch(void* const* d_in, const int* in_sizes, int n_in,
                              void* d_out, int out_size, void* d_ws, size_t ws_size,
                              hipStream_t stream) {
    const float* x    = (const float*)d_in[0];  // (B,E,C,I) fp32
    const int*   idx  = (const int*)  d_in[1];  // (B,E,C) int32
    const float* gate = (const float*)d_in[2];  // (B,E,C) fp32
    const float* w    = (const float*)d_in[3];  // (E,O,I) fp32
    const float* bias = (const float*)d_in[4];  // (O,) fp32
    float* out = (float*)d_out;

    uint4* wh4 = (uint4*)d_ws;  // 512 KB packed f16 weights

    prep_w<<<(En * 4 * 4 * On) / 256, 256, 0, stream>>>((const float4*)w, wh4);
    hipMemsetAsync(d_out, 0, (size_t)out_size, stream);  // capture-safe

    const int nblk = Bn * En * (Cn / TT);  // 1024
    gemm_scatter<<<nblk, 256, 0, stream>>>(x, idx, gate, wh4, bias, out);
}